// Round 9
// baseline (124.158 us; speedup 1.0000x reference)
//
#include <hip/hip_runtime.h>
#include <math.h>

#define B_      4
#define NH      8
#define HD      32
#define WINNUM  49
#define LWIN    3136
#define NTOK    3137
#define NPIX    12544     // B * 56 * 56
#define MROWS   12548     // NPIX + 4 cls rows
// 256^-0.5 * log2(e): scores land in exp2 domain (no bias: cancels in norm)
#define SCALE_L2E 0.09016844005556021f

typedef _Float16 half_t;
using half8 = __attribute__((ext_vector_type(8))) half_t;
using half4 = __attribute__((ext_vector_type(4))) half_t;
using f32x4 = __attribute__((ext_vector_type(4))) float;

__device__ __forceinline__ unsigned pack2(float a, float b) {
    auto h = __builtin_amdgcn_cvt_pkrtz(a, b);   // __fp16 ext_vector(2)
    return __builtin_bit_cast(unsigned, h);
}
__device__ __forceinline__ half8 as_h8(int4 v) {
    return __builtin_bit_cast(half8, v);
}

// ---------------------------------------------------------------------------
// prep: weight/const conversions only. Wqkvt (768,256), Wot (256,256)
// transposed fp16; lkh (9,256) + lbh (256) fp16 lepe constants.
// ---------------------------------------------------------------------------
__global__ __launch_bounds__(256)
void prep(const float* __restrict__ Wqkv, const float* __restrict__ Wo,
          const float* __restrict__ lk, const float* __restrict__ lb,
          half_t* __restrict__ Wqkvt, half_t* __restrict__ Wot,
          half_t* __restrict__ lkh, half_t* __restrict__ lbh)
{
    const int idx = blockIdx.x * 256 + threadIdx.x;
    const int stride = gridDim.x * 256;
    for (int i = idx; i < 768 * 256; i += stride) {
        int n = i >> 8, k = i & 255;
        Wqkvt[i] = (half_t)Wqkv[k * 768 + n];
    }
    for (int i = idx; i < 256 * 256; i += stride) {
        int n = i >> 8, k = i & 255;
        Wot[i] = (half_t)Wo[k * 256 + n];
    }
    for (int i = idx; i < 9 * 256; i += stride) lkh[i] = (half_t)lk[i];
    for (int i = idx; i < 256; i += stride) lbh[i] = (half_t)lb[i];
}

// ---------------------------------------------------------------------------
// qkv_gemm: C = [x;cls] @ Wqkv + bqkv via fp16 MFMA, 128x128 tile, 4 waves.
// A staged from fp32 with cvt_pkrtz in registers (reg-staged double buffer).
// Epilogue scatters q/k/v to attention layouts.
// ---------------------------------------------------------------------------
__global__ __launch_bounds__(256)
void qkv_gemm(const float* __restrict__ x, const float* __restrict__ cls,
              const half_t* __restrict__ Bt, const float* __restrict__ bqkv,
              half_t* __restrict__ qh, half_t* __restrict__ kh,
              half_t* __restrict__ khcls, half_t* __restrict__ vh,
              half_t* __restrict__ vplain)
{
    __shared__ __align__(16) short As[2][128 * 40];
    __shared__ __align__(16) short Bs[2][128 * 40];
    const int m0 = blockIdx.y * 128, n0 = blockIdx.x * 128;
    const int tid = threadIdx.x;
    const int lane = tid & 63, wv = tid >> 6;
    const int wm = wv >> 1, wn = wv & 1;
    const int qi = lane & 15, g = lane >> 4;
    f32x4 acc[4][4] = {};

    float4 rfa[2][2];
    int4 rb[2];
    auto issue = [&](int k0) {
#pragma unroll
        for (int i = 0; i < 2; ++i) {
            int ch = tid + 256 * i;
            int row = ch >> 2, kc = (ch & 3) * 8;
            int m = m0 + row;
            if (m < MROWS) {
                const float* src = ((m < NPIX) ? (x + (size_t)m * 256)
                                               : (cls + (size_t)(m - NPIX) * 256)) + k0 + kc;
                rfa[i][0] = *(const float4*)src;
                rfa[i][1] = *(const float4*)(src + 4);
            } else {
                rfa[i][0] = rfa[i][1] = make_float4(0.f, 0.f, 0.f, 0.f);
            }
            rb[i] = *(const int4*)(Bt + (size_t)(n0 + row) * 256 + k0 + kc);
        }
    };
    auto commit = [&](int bu) {
#pragma unroll
        for (int i = 0; i < 2; ++i) {
            int ch = tid + 256 * i;
            int row = ch >> 2, kc = (ch & 3) * 8;
            uint4 pa = make_uint4(pack2(rfa[i][0].x, rfa[i][0].y), pack2(rfa[i][0].z, rfa[i][0].w),
                                  pack2(rfa[i][1].x, rfa[i][1].y), pack2(rfa[i][1].z, rfa[i][1].w));
            *(uint4*)&As[bu][row * 40 + kc] = pa;
            *(int4*)&Bs[bu][row * 40 + kc] = rb[i];
        }
    };

    issue(0); commit(0);
    __syncthreads();
    int buf = 0;
    for (int s = 0; s < 8; ++s) {
        if (s < 7) issue((s + 1) * 32);
        half8 af[4], bf[4];
#pragma unroll
        for (int f = 0; f < 4; ++f) {
            af[f] = *(const half8*)&As[buf][(wm * 64 + f * 16 + qi) * 40 + g * 8];
            bf[f] = *(const half8*)&Bs[buf][(wn * 64 + f * 16 + qi) * 40 + g * 8];
        }
#pragma unroll
        for (int fm = 0; fm < 4; ++fm)
#pragma unroll
            for (int fn = 0; fn < 4; ++fn)
                acc[fm][fn] = __builtin_amdgcn_mfma_f32_16x16x32_f16(af[fm], bf[fn], acc[fm][fn], 0, 0, 0);
        if (s < 7) commit(buf ^ 1);
        __syncthreads();
        buf ^= 1;
    }

    const int part = n0 >> 8;
    int nhv[4], dv[4];
    float bq[4];
#pragma unroll
    for (int fn = 0; fn < 4; ++fn) {
        int n = n0 + wn * 64 + fn * 16 + qi;
        bq[fn] = bqkv[n];
        int c = n & 255;
        nhv[fn] = c >> 5; dv[fn] = c & 31;
    }
#pragma unroll
    for (int fm = 0; fm < 4; ++fm) {
#pragma unroll
        for (int r = 0; r < 4; ++r) {
            int m = m0 + wm * 64 + fm * 16 + g * 4 + r;
            if (m >= MROWS) continue;
            int b, tok;
            if (m < NPIX) {
                b = m / LWIN;
                int p = m - b * LWIN;
                int hh = p / 56, ww = p - hh * 56;
                tok = ((hh >> 3) * 7 + (ww >> 3)) * 64 + ((hh & 7) << 3) + (ww & 7);
            } else { b = m - NPIX; tok = LWIN; }
#pragma unroll
            for (int fn = 0; fn < 4; ++fn) {
                float val = acc[fm][fn][r] + bq[fn];
                size_t bh = (size_t)(b * NH + nhv[fn]);
                int d = dv[fn];
                if (part == 0) {
                    qh[(bh * NTOK + tok) * 32 + d] = (half_t)(val * SCALE_L2E);
                } else if (part == 1) {
                    if (tok < LWIN) kh[(bh * WINNUM + (tok >> 6)) * 2560 + (tok & 63) * 40 + d] = (half_t)val;
                    else            khcls[bh * 32 + d] = (half_t)val;
                } else {
                    vplain[(bh * NTOK + tok) * 32 + d] = (half_t)val;
                    if (tok < LWIN) vh[(bh * WINNUM + (tok >> 6)) * 2560 + d * 80 + (tok & 63)] = (half_t)val;
                }
            }
        }
    }
}

// ---------------------------------------------------------------------------
// win_attn: barrier-free window attention + FUSED lepe conv epilogue.
// 4 independent waves/block; K/V fragments global->register; no bias
// (cancels in softmax); l accumulated via ones-row MFMA on P fragments.
// Blocks [1568,1824) = cls-query partials.
// ---------------------------------------------------------------------------
__global__ __launch_bounds__(256)
void win_attn(const half_t* __restrict__ qh, const half_t* __restrict__ kh,
              const half_t* __restrict__ khcls, const half_t* __restrict__ vh,
              const half_t* __restrict__ vplain, const int* __restrict__ mask,
              const half_t* __restrict__ lkh, const half_t* __restrict__ lbh,
              half_t* __restrict__ tg, float* __restrict__ clspart)
{
    const int id = blockIdx.x;
    const int tid = threadIdx.x;
    __shared__ __align__(16) short Plds[4][16 * 72];   // 9216 B
    __shared__ float redc[4 * 33];
    const int lane = tid & 63, wv = tid >> 6;

    if (id >= 1568) {
        // ---------------- cls partial block ----------------
        const int cid = id - 1568;
        const int bh = cid >> 3;
        const int chunk = cid & 7;
        const int wstart = chunk * 6;
        const int nw = (chunk < 7) ? 6 : 7;
        const int nkeys = nw * 64;

        float q[32];
        {
            const half_t* qp = qh + ((size_t)bh * NTOK + LWIN) * 32;
#pragma unroll
            for (int d = 0; d < 32; ++d) q[d] = (float)qp[d];
        }
        float l = 0.f, o[32];
#pragma unroll
        for (int d = 0; d < 32; ++d) o[d] = 0.f;

        const half_t* kwb = kh + (size_t)bh * (WINNUM * 2560) + wstart * 2560;
        const half_t* vb  = vplain + ((size_t)bh * NTOK + wstart * 64) * 32;

        for (int kk = tid; kk < nkeys; kk += 256) {
            const half_t* kp = kwb + (kk >> 6) * 2560 + (kk & 63) * 40;
            float s = 0.f;
#pragma unroll
            for (int c8 = 0; c8 < 4; ++c8) {
                half8 kv = *(const half8*)(kp + c8 * 8);
#pragma unroll
                for (int j = 0; j < 8; ++j) s += q[c8 * 8 + j] * (float)kv[j];
            }
            float pp = exp2f(s);
            l += pp;
            const half_t* vp = vb + (size_t)kk * 32;
#pragma unroll
            for (int c8 = 0; c8 < 4; ++c8) {
                half8 vvv = *(const half8*)(vp + c8 * 8);
#pragma unroll
                for (int j = 0; j < 8; ++j) o[c8 * 8 + j] += pp * (float)vvv[j];
            }
        }
        if (chunk == 7 && tid == 0) {    // cls key
            const half_t* kp = khcls + bh * 32;
            float s = 0.f;
#pragma unroll
            for (int d = 0; d < 32; ++d) s += q[d] * (float)kp[d];
            float pp = exp2f(s);
            l += pp;
            const half_t* vp = vplain + ((size_t)bh * NTOK + LWIN) * 32;
#pragma unroll
            for (int d = 0; d < 32; ++d) o[d] += pp * (float)vp[d];
        }
#pragma unroll
        for (int off = 1; off < 64; off <<= 1) {
            l += __shfl_xor(l, off);
#pragma unroll
            for (int d = 0; d < 32; ++d) o[d] += __shfl_xor(o[d], off);
        }
        if (lane == 0) {
#pragma unroll
            for (int d = 0; d < 32; ++d) redc[wv * 33 + d] = o[d];
            redc[wv * 33 + 32] = l;
        }
        __syncthreads();
        if (tid < 33) {
            float s = redc[tid] + redc[33 + tid] + redc[66 + tid] + redc[99 + tid];
            clspart[(bh * 8 + chunk) * 33 + tid] = s;
        }
        return;
    }

    // ---------------- window-attention block (no barriers) ----------------
    const int sw = (id & 7) * 196 + (id >> 3);   // XCD-chunked swizzle
    const int wi = sw % 49;
    const int bh = sw / 49;
    const int b = bh >> 3, nh = bh & 7;

    const int g = lane >> 4, qi = lane & 15;
    const int qrow = wi * 64 + wv * 16 + qi;

    half8 aq = *(const half8*)(qh + ((size_t)bh * NTOK + qrow) * 32 + g * 8);

    // ones A-fragment: row 0 = 1 (lanes qi==0), else 0
    half8 onesA = {};
    if (qi == 0) {
#pragma unroll
        for (int j = 0; j < 8; ++j) onesA[j] = (half_t)1.0f;
    }

    f32x4 acc[2] = {{0.f,0.f,0.f,0.f},{0.f,0.f,0.f,0.f}};
    f32x4 acc_l = {0.f,0.f,0.f,0.f};

    const int* mrow = mask + (b * WINNUM + wi) * WINNUM;
    int mv = (lane < WINNUM) ? mrow[lane] : 0;
    unsigned long long rem = __ballot(mv != 0);

    const half_t* kwin = kh + (size_t)bh * (WINNUM * 2560);
    const half_t* vwin = vh + (size_t)bh * (WINNUM * 2560);
    const int koff = qi * 40 + g * 8;
    const int voff = qi * 80 + g * 8;

    short* pw = &Plds[wv][qi * 72];
    const short* prd = &Plds[wv][qi * 72 + g * 8];

    while (rem) {
        const int wj = __builtin_ctzll(rem);
        rem &= rem - 1;
        const half_t* kb = kwin + wj * 2560 + koff;
        const half_t* vb = vwin + wj * 2560 + voff;
        int4 kf0 = *(const int4*)(kb);
        int4 kf1 = *(const int4*)(kb + 640);
        int4 kf2 = *(const int4*)(kb + 1280);
        int4 kf3 = *(const int4*)(kb + 1920);
        int4 vf00 = *(const int4*)(vb);
        int4 vf01 = *(const int4*)(vb + 32);
        int4 vf10 = *(const int4*)(vb + 1280);
        int4 vf11 = *(const int4*)(vb + 1312);

        f32x4 st[4];
        __builtin_amdgcn_s_setprio(1);
        st[0] = __builtin_amdgcn_mfma_f32_16x16x32_f16(as_h8(kf0), aq, (f32x4){0.f,0.f,0.f,0.f}, 0, 0, 0);
        st[1] = __builtin_amdgcn_mfma_f32_16x16x32_f16(as_h8(kf1), aq, (f32x4){0.f,0.f,0.f,0.f}, 0, 0, 0);
        st[2] = __builtin_amdgcn_mfma_f32_16x16x32_f16(as_h8(kf2), aq, (f32x4){0.f,0.f,0.f,0.f}, 0, 0, 0);
        st[3] = __builtin_amdgcn_mfma_f32_16x16x32_f16(as_h8(kf3), aq, (f32x4){0.f,0.f,0.f,0.f}, 0, 0, 0);
        __builtin_amdgcn_s_setprio(0);

        // p = exp2(s) (no bias), pack to per-wave LDS
#pragma unroll
        for (int t = 0; t < 4; ++t) {
            float p0 = exp2f(st[t][0]);
            float p1 = exp2f(st[t][1]);
            float p2 = exp2f(st[t][2]);
            float p3 = exp2f(st[t][3]);
            uint2 pk = make_uint2(pack2(p0, p1), pack2(p2, p3));
            *(uint2*)&pw[t * 16 + 4 * g] = pk;
        }
        half8 bp0 = *(const half8*)(prd);
        half8 bp1 = *(const half8*)(prd + 32);
        __builtin_amdgcn_s_setprio(1);
        acc[0] = __builtin_amdgcn_mfma_f32_16x16x32_f16(as_h8(vf00), bp0, acc[0], 0, 0, 0);
        acc[1] = __builtin_amdgcn_mfma_f32_16x16x32_f16(as_h8(vf10), bp0, acc[1], 0, 0, 0);
        acc_l  = __builtin_amdgcn_mfma_f32_16x16x32_f16(onesA, bp0, acc_l, 0, 0, 0);
        acc[0] = __builtin_amdgcn_mfma_f32_16x16x32_f16(as_h8(vf01), bp1, acc[0], 0, 0, 0);
        acc[1] = __builtin_amdgcn_mfma_f32_16x16x32_f16(as_h8(vf11), bp1, acc[1], 0, 0, 0);
        acc_l  = __builtin_amdgcn_mfma_f32_16x16x32_f16(onesA, bp1, acc_l, 0, 0, 0);
        __builtin_amdgcn_s_setprio(0);
    }

    // l for query qi lives in D row 0 = lane qi (g=0), reg 0: broadcast
    float lwin = __shfl(acc_l[0], qi);

    // cls key (fp32 scalar)
    float kcls[8], vcls[2][4];
#pragma unroll
    for (int j = 0; j < 8; ++j) kcls[j] = (float)khcls[bh * 32 + g * 8 + j];
    {
        const half_t* vcb = vplain + ((size_t)bh * NTOK + LWIN) * 32;
#pragma unroll
        for (int h2 = 0; h2 < 2; ++h2)
#pragma unroll
            for (int r = 0; r < 4; ++r) vcls[h2][r] = (float)vcb[h2 * 16 + g * 4 + r];
    }
    float sc = 0.f;
#pragma unroll
    for (int j = 0; j < 8; ++j) sc += (float)aq[j] * kcls[j];
    sc += __shfl_xor(sc, 16);
    sc += __shfl_xor(sc, 32);
    float pc = exp2f(sc);
    float l = lwin + pc;
#pragma unroll
    for (int h2 = 0; h2 < 2; ++h2)
#pragma unroll
        for (int r = 0; r < 4; ++r) acc[h2][r] += pc * vcls[h2][r];

    // ---- fused lepe: conv3x3 depthwise on v for this pixel's channels ----
    const int kk = wv * 16 + qi;
    const int hh = (wi / 7) * 8 + (kk >> 3);
    const int ww = (wi % 7) * 8 + (kk & 7);
    const int c0 = nh * 32;
    half4 conv[2];
    conv[0] = *(const half4*)(lbh + c0 + g * 4);
    conv[1] = *(const half4*)(lbh + c0 + 16 + g * 4);
    {
        const half_t* vpb = vplain + (size_t)bh * NTOK * 32 + g * 4;
#pragma unroll
        for (int dh = -1; dh <= 1; ++dh) {
            int hn = hh + dh;
            if (hn < 0 || hn >= 56) continue;
#pragma unroll
            for (int dw = -1; dw <= 1; ++dw) {
                int wn = ww + dw;
                if (wn < 0 || wn >= 56) continue;
                int tok2 = ((hn >> 3) * 7 + (wn >> 3)) * 64 + ((hn & 7) << 3) + (wn & 7);
                int tap = (dh + 1) * 3 + (dw + 1);
                const half_t* vp = vpb + (size_t)tok2 * 32;
                half4 v0 = *(const half4*)(vp);
                half4 v1 = *(const half4*)(vp + 16);
                half4 k0 = *(const half4*)(lkh + tap * 256 + c0 + g * 4);
                half4 k1 = *(const half4*)(lkh + tap * 256 + c0 + 16 + g * 4);
                conv[0] += v0 * k0;
                conv[1] += v1 * k1;
            }
        }
    }

    // write t = O/l + conv to tg[pix][nh*32 + d], d = 16*h2 + 4*g + r
    {
        float inv = 1.f / l;
        size_t pix = (size_t)b * LWIN + hh * 56 + ww;
        half_t* tp = tg + pix * 256 + nh * 32;
#pragma unroll
        for (int h2 = 0; h2 < 2; ++h2) {
            half4 hv;
#pragma unroll
            for (int r = 0; r < 4; ++r)
                hv[r] = (half_t)(acc[h2][r] * inv + (float)conv[h2][r]);
            *(half4*)(tp + h2 * 16 + g * 4) = hv;
        }
    }
}

// ---------------------------------------------------------------------------
// cls_norm: normalize cls partials into tg cls rows. One block.
// ---------------------------------------------------------------------------
__global__ __launch_bounds__(256)
void cls_norm(const float* __restrict__ clspart, half_t* __restrict__ tg)
{
    const int c = threadIdx.x;
    const int nh = c >> 5, d = c & 31;
#pragma unroll
    for (int b = 0; b < 4; ++b) {
        int bh = b * NH + nh;
        float os = 0.f, ls = 0.f;
#pragma unroll
        for (int ch = 0; ch < 8; ++ch) {
            os += clspart[(bh * 8 + ch) * 33 + d];
            ls += clspart[(bh * 8 + ch) * 33 + 32];
        }
        tg[(size_t)(NPIX + b) * 256 + c] = (half_t)(os / ls);
    }
}

// ---------------------------------------------------------------------------
// out_gemm: out = t @ Wo + bo (fp16 MFMA, fp32 out). 64x128 tile -> 394
// blocks. Reg-staged double buffer.
// ---------------------------------------------------------------------------
__global__ __launch_bounds__(256)
void out_gemm(const half_t* __restrict__ th, const half_t* __restrict__ Bt,
              const float* __restrict__ bo, float* __restrict__ out)
{
    __shared__ __align__(16) short As[2][64 * 40];
    __shared__ __align__(16) short Bs[2][128 * 40];
    const int m0 = blockIdx.y * 64, n0 = blockIdx.x * 128;
    const int tid = threadIdx.x;
    const int lane = tid & 63, wv = tid >> 6;
    const int wm = wv >> 1, wn = wv & 1;
    const int qi = lane & 15, g = lane >> 4;
    f32x4 acc[2][4] = {};

    int4 ra, rb[2];
    auto issue = [&](int k0) {
        {
            int row = tid >> 2, kc = (tid & 3) * 8;
            int m = m0 + row;
            ra = (m < MROWS) ? *(const int4*)(th + (size_t)m * 256 + k0 + kc)
                             : make_int4(0, 0, 0, 0);
        }
#pragma unroll
        for (int i = 0; i < 2; ++i) {
            int ch = tid + 256 * i;
            int row = ch >> 2, kc = (ch & 3) * 8;
            rb[i] = *(const int4*)(Bt + (size_t)(n0 + row) * 256 + k0 + kc);
        }
    };
    auto commit = [&](int bu) {
        {
            int row = tid >> 2, kc = (tid & 3) * 8;
            *(int4*)&As[bu][row * 40 + kc] = ra;
        }
#pragma unroll
        for (int i = 0; i < 2; ++i) {
            int ch = tid + 256 * i;
            int row = ch >> 2, kc = (ch & 3) * 8;
            *(int4*)&Bs[bu][row * 40 + kc] = rb[i];
        }
    };

    issue(0); commit(0);
    __syncthreads();
    int buf = 0;
    for (int s = 0; s < 8; ++s) {
        if (s < 7) issue((s + 1) * 32);
        half8 af[2], bf[4];
#pragma unroll
        for (int f = 0; f < 2; ++f)
            af[f] = *(const half8*)&As[buf][(wm * 32 + f * 16 + qi) * 40 + g * 8];
#pragma unroll
        for (int f = 0; f < 4; ++f)
            bf[f] = *(const half8*)&Bs[buf][(wn * 64 + f * 16 + qi) * 40 + g * 8];
#pragma unroll
        for (int fm = 0; fm < 2; ++fm)
#pragma unroll
            for (int fn = 0; fn < 4; ++fn)
                acc[fm][fn] = __builtin_amdgcn_mfma_f32_16x16x32_f16(af[fm], bf[fn], acc[fm][fn], 0, 0, 0);
        if (s < 7) commit(buf ^ 1);
        __syncthreads();
        buf ^= 1;
    }

    float bov[4];
    int nn[4];
#pragma unroll
    for (int fn = 0; fn < 4; ++fn) {
        nn[fn] = n0 + wn * 64 + fn * 16 + qi;
        bov[fn] = bo[nn[fn]];
    }
#pragma unroll
    for (int fm = 0; fm < 2; ++fm)
#pragma unroll
        for (int r = 0; r < 4; ++r) {
            int m = m0 + wm * 32 + fm * 16 + g * 4 + r;
            if (m >= MROWS) continue;
#pragma unroll
            for (int fn = 0; fn < 4; ++fn)
                out[(size_t)m * 256 + nn[fn]] = acc[fm][fn][r] + bov[fn];
        }
}

// ---------------------------------------------------------------------------
extern "C" void kernel_launch(void* const* d_in, const int* in_sizes, int n_in,
                              void* d_out, int out_size, void* d_ws, size_t ws_size,
                              hipStream_t stream)
{
    const float* x    = (const float*)d_in[0];
    const float* cls  = (const float*)d_in[1];
    const int*   mask = (const int*)d_in[2];
    const float* Wqkv = (const float*)d_in[5];
    const float* bqkv = (const float*)d_in[6];
    const float* Wo   = (const float*)d_in[7];
    const float* bo   = (const float*)d_in[8];
    const float* lk   = (const float*)d_in[9];
    const float* lb   = (const float*)d_in[10];
    float* out = (float*)d_out;

    char* w = (char*)d_ws;
    half_t* qh     = (half_t*)w;  w += 6424576;   // 32*3137*32*2
    half_t* kh     = (half_t*)w;  w += 8028160;   // 32*49*2560*2
    half_t* khcls  = (half_t*)w;  w += 2048;
    half_t* vh     = (half_t*)w;  w += 8028160;   // 32*49*2560*2
    half_t* vplain = (half_t*)w;  w += 6424576;
    half_t* Wqkvt  = (half_t*)w;  w += 393216;
    half_t* Wot    = (half_t*)w;  w += 131072;
    half_t* th     = (half_t*)w;  w += 6424576;   // 12548*256*2
    float*  clspart= (float*)w;   w += 33792;     // 32*8*33*4
    half_t* lkh    = (half_t*)w;  w += 4608;      // 9*256*2
    half_t* lbh    = (half_t*)w;  w += 512;

    prep<<<256, 256, 0, stream>>>(Wqkv, Wo, lk, lb, Wqkvt, Wot, lkh, lbh);
    qkv_gemm<<<dim3(6, 99), 256, 0, stream>>>(x, cls, Wqkvt, bqkv, qh, kh, khcls, vh, vplain);
    win_attn<<<1824, 256, 0, stream>>>(qh, kh, khcls, vh, vplain, mask, lkh, lbh, th, clspart);
    cls_norm<<<1, 256, 0, stream>>>(clspart, th);
    out_gemm<<<dim3(2, 197), 256, 0, stream>>>(th, Wot, bo, out);
}